// Round 2
// baseline (3337.144 us; speedup 1.0000x reference)
//
#include <hip/hip_runtime.h>

#define N_NODES 50000
#define N_EDGES 800000
#define IN_DIM  1024
#define COUT    127
#define H1      256
#define H2      128
#define LDA     256          // row stride (elements) of xa / x2 / P
#define NBLK    1024         // 4 blocks/CU on 256 CUs -- co-resident by construction
#define NTHR    256
#define TOTTHR  (NBLK * NTHR)        // 262144
#define NWAVE   (TOTTHR / 64)        // 4096
#define CH      49                   // nodes per block in the scan (49*1024 >= 50000)
#define NTILE   (391 * 4)            // gemm tiles: 391 m-blocks x 4 n-blocks
#define NROWS   4096                 // partial-pool rows (one per wave)
#define LDSS    72                   // LDS row stride (elems): 144 B -> 2-way only

typedef __bf16 bf16;
typedef __attribute__((ext_vector_type(8))) __bf16 bf16x8;
typedef __attribute__((ext_vector_type(2))) __bf16 bf16x2;
typedef __attribute__((ext_vector_type(4))) float floatx4;

__device__ __forceinline__ float blo(unsigned int u) { return __uint_as_float(u << 16); }
__device__ __forceinline__ float bhi(unsigned int u) { return __uint_as_float(u & 0xffff0000u); }

struct Par {
    const float* h; const int* src; const int* dst;
    const float* cw; const float* cb;
    const float* ws1; const float* wn1; const float* b1;
    const float* ws2; const float* wn2; const float* b2;
    const float* f1w; const float* f1b; const float* f2w; const float* f2b;
    const float* f3w; const float* f3b;
    float* out;
    bf16* xa; bf16* x2; bf16* wt1; bf16* wt2;
    int* deg; int* rowp; int* esrc; float* part; float* hg; int* bsum; int* bar;
};

// ---- grid barrier: 32 leaf counters + 1 root per sync point ---------------
// Release: all waves __threadfence() (wbL2) before arrival; acquire: all waves
// __threadfence() (invL2) after. Cross-XCD visibility per Guideline 16.
__device__ __forceinline__ void gsync(int* bar, int idx) {
    __syncthreads();
    __threadfence();
    if (threadIdx.x == 0) {
        int* leaf = bar + idx * 33 + (blockIdx.x & 31);
        int* root = bar + idx * 33 + 32;
        int a = __hip_atomic_fetch_add(leaf, 1, __ATOMIC_ACQ_REL, __HIP_MEMORY_SCOPE_AGENT);
        if (a == (NBLK / 32) - 1)
            __hip_atomic_fetch_add(root, 1, __ATOMIC_ACQ_REL, __HIP_MEMORY_SCOPE_AGENT);
        while (__hip_atomic_load(root, __ATOMIC_ACQUIRE, __HIP_MEMORY_SCOPE_AGENT) != 32) {
            __builtin_amdgcn_s_sleep(4);
        }
    }
    __syncthreads();
    __threadfence();
}

// ---- conv1d slice: h[N,1024] -> xa[:, 0:128] bf16 (col 127 = 0) -----------
__device__ __forceinline__ void conv_slice(const Par& p, int lo, int hi, int gtid) {
    int t = gtid & 127;
    int g = gtid >> 7;                             // 0..2047
    float wv[10];
    #pragma unroll
    for (int j = 0; j < 10; ++j) wv[j] = p.cw[j];
    float bb = p.cb[0];
    for (int n = lo + g; n < hi; n += 2048) {
        const float* hr = p.h + (size_t)n * IN_DIM;
        float r = 0.f;
        if (t < COUT) {
            const float* q = hr + t * 8;           // 32B aligned
            float4 a = *(const float4*)q;
            float4 c = *(const float4*)(q + 4);
            float2 d = *(const float2*)(q + 8);
            float s = bb;
            s += a.x * wv[0] + a.y * wv[1] + a.z * wv[2] + a.w * wv[3];
            s += c.x * wv[4] + c.y * wv[5] + c.z * wv[6] + c.w * wv[7];
            s += d.x * wv[8] + d.y * wv[9];
            r = fmaxf(s, 0.f);
        }
        p.xa[(size_t)n * LDA + t] = (bf16)r;
    }
}

// ---- MFMA GEMM phase: out[N,256] = (relu?)(X[N,256] @ W (+bias)), bf16 ----
__device__ __forceinline__ void gemm_phase(const bf16* __restrict__ X,
                                           const bf16* __restrict__ WT,
                                           const float* __restrict__ bias,
                                           bf16* __restrict__ out, bool relu,
                                           bf16* As, bf16* Bs, int bid, int tid) {
    int lane = tid & 63, w = tid >> 6;
    int quad = lane >> 4, l16 = lane & 15;
    for (int tile = bid; tile < NTILE; tile += NBLK) {
        int nb = tile / 391, mb = tile - nb * 391;
        int m0 = mb * 128, n0 = nb * 64;
        floatx4 acc[2][4] = {};
        for (int k0 = 0; k0 < 256; k0 += 64) {
            uint4 av[4], bv[2];
            #pragma unroll
            for (int i = 0; i < 4; ++i) {
                int c = tid + 256 * i;
                int row = c >> 3, col = (c & 7) * 8;
                int gr = m0 + row;
                av[i] = (gr < N_NODES) ? *(const uint4*)(X + (size_t)gr * LDA + k0 + col)
                                       : make_uint4(0u, 0u, 0u, 0u);
            }
            #pragma unroll
            for (int i = 0; i < 2; ++i) {
                int c = tid + 256 * i;
                int row = c >> 3, col = (c & 7) * 8;
                bv[i] = *(const uint4*)(WT + (size_t)(n0 + row) * 256 + k0 + col);
            }
            __syncthreads();
            #pragma unroll
            for (int i = 0; i < 4; ++i) {
                int c = tid + 256 * i;
                int row = c >> 3, col = (c & 7) * 8;
                *(uint4*)&As[row * LDSS + col] = av[i];
            }
            #pragma unroll
            for (int i = 0; i < 2; ++i) {
                int c = tid + 256 * i;
                int row = c >> 3, col = (c & 7) * 8;
                *(uint4*)&Bs[row * LDSS + col] = bv[i];
            }
            __syncthreads();
            #pragma unroll
            for (int ks = 0; ks < 2; ++ks) {
                int kin = ks * 32 + quad * 8;
                bf16x8 a0 = *(const bf16x8*)&As[(w * 32 + l16) * LDSS + kin];
                bf16x8 a1 = *(const bf16x8*)&As[(w * 32 + 16 + l16) * LDSS + kin];
                bf16x8 b0 = *(const bf16x8*)&Bs[(l16) * LDSS + kin];
                bf16x8 b1 = *(const bf16x8*)&Bs[(16 + l16) * LDSS + kin];
                bf16x8 b2 = *(const bf16x8*)&Bs[(32 + l16) * LDSS + kin];
                bf16x8 b3 = *(const bf16x8*)&Bs[(48 + l16) * LDSS + kin];
                acc[0][0] = __builtin_amdgcn_mfma_f32_16x16x32_bf16(a0, b0, acc[0][0], 0, 0, 0);
                acc[0][1] = __builtin_amdgcn_mfma_f32_16x16x32_bf16(a0, b1, acc[0][1], 0, 0, 0);
                acc[0][2] = __builtin_amdgcn_mfma_f32_16x16x32_bf16(a0, b2, acc[0][2], 0, 0, 0);
                acc[0][3] = __builtin_amdgcn_mfma_f32_16x16x32_bf16(a0, b3, acc[0][3], 0, 0, 0);
                acc[1][0] = __builtin_amdgcn_mfma_f32_16x16x32_bf16(a1, b0, acc[1][0], 0, 0, 0);
                acc[1][1] = __builtin_amdgcn_mfma_f32_16x16x32_bf16(a1, b1, acc[1][1], 0, 0, 0);
                acc[1][2] = __builtin_amdgcn_mfma_f32_16x16x32_bf16(a1, b2, acc[1][2], 0, 0, 0);
                acc[1][3] = __builtin_amdgcn_mfma_f32_16x16x32_bf16(a1, b3, acc[1][3], 0, 0, 0);
            }
        }
        float bvv[4] = {};
        if (relu) {
            #pragma unroll
            for (int nt = 0; nt < 4; ++nt) bvv[nt] = bias[n0 + nt * 16 + l16];
        }
        #pragma unroll
        for (int mt = 0; mt < 2; ++mt) {
            #pragma unroll
            for (int r = 0; r < 4; ++r) {
                int m = m0 + w * 32 + mt * 16 + quad * 4 + r;
                if (m < N_NODES) {
                    #pragma unroll
                    for (int nt = 0; nt < 4; ++nt) {
                        float v = acc[mt][nt][r];
                        if (relu) v = fmaxf(v + bvv[nt], 0.f);
                        out[(size_t)m * LDA + n0 + nt * 16 + l16] = (bf16)v;
                    }
                }
            }
        }
        // LDS reuse across tiles is safe: next iteration's first touch of LDS
        // is preceded by __syncthreads() after register staging.
    }
}

// ============================ the mega-kernel ===============================
__global__ __launch_bounds__(NTHR, 4) void mega(Par p) {
    __shared__ bf16 As[128 * LDSS];                // 18432 B
    __shared__ bf16 Bs[64 * LDSS];                 //  9216 B
    __shared__ int   s4[4];
    __shared__ float rls[4];
    __shared__ float h0[128], y1[64], y2[32];

    const int tid  = threadIdx.x;
    const int bid  = blockIdx.x;
    const int gtid = bid * NTHR + tid;
    const int lane = tid & 63;
    const int wv   = tid >> 6;                     // wave-in-block 0..3
    const int gwid = bid * 4 + wv;                 // global wave id 0..4095

    // ---- A: pad/transpose weights + zero deg --------------------------------
    {
        int i = gtid;
        if (i < 131072) {
            int j = i & 65535;
            int n = j >> 8, k = j & 255;
            if (i < 65536) {
                float v = 0.f;
                if (k < COUT)                        v = p.ws1[k * H1 + n];
                else if (k >= 128 && k < 128 + COUT) v = p.wn1[(k - 128) * H1 + n];
                p.wt1[j] = (bf16)v;
            } else {
                float v = (n < H2) ? p.ws2[k * H2 + n] : p.wn2[k * H2 + (n - H2)];
                p.wt2[j] = (bf16)v;
            }
        }
        if (i < 50048) p.deg[i] = 0;
    }
    gsync(p.bar, 0);

    // ---- B: degree atomics + conv slice 0 -----------------------------------
    for (int e = gtid; e < N_EDGES; e += TOTTHR) atomicAdd(&p.deg[p.dst[e]], 1);
    conv_slice(p, 0, 10000, gtid);
    gsync(p.bar, 1);

    // ---- C: block-local scan (wave 0) + conv slice 1 ------------------------
    int sv = 0, sincl = 0;                          // persist to phase E
    if (wv == 0) {
        int n = bid * CH + lane;
        sv = (lane < CH && n < N_NODES) ? p.deg[n] : 0;
        sincl = sv;
        #pragma unroll
        for (int off = 1; off < 64; off <<= 1) {
            int t = __shfl_up(sincl, off);
            if (lane >= off) sincl += t;
        }
        int tot = __shfl(sincl, CH - 1);
        if (lane == 0) p.bsum[bid] = tot;
    }
    conv_slice(p, 10000, 20000, gtid);
    gsync(p.bar, 2);

    // ---- D: scan of 1024 block sums (block 0) + conv slice 2 ----------------
    if (bid == 0) {
        int4 xv = ((const int4*)p.bsum)[tid];       // elems 4t..4t+3
        int i1 = xv.x + xv.y, i2 = i1 + xv.z, i3 = i2 + xv.w;
        int s = i3;
        #pragma unroll
        for (int off = 1; off < 64; off <<= 1) {
            int t = __shfl_up(s, off);
            if (lane >= off) s += t;
        }
        if (lane == 63) s4[wv] = s;
        __syncthreads();
        if (tid == 0) {
            int a = 0;
            for (int j = 0; j < 4; ++j) { int t = s4[j]; s4[j] = a; a += t; }
            p.rowp[N_NODES] = a;                    // total edge count
        }
        __syncthreads();
        int excl = s4[wv] + (s - i3);               // exclusive before this thread's 4
        ((int4*)p.bsum)[tid] = make_int4(excl, excl + xv.x, excl + i1, excl + i2);
    }
    conv_slice(p, 20000, 30000, gtid);
    gsync(p.bar, 3);

    // ---- E: write rowptr + cursor (deg alias) + conv slice 3 ----------------
    if (wv == 0) {
        int off = p.bsum[bid];
        int n = bid * CH + lane;
        if (lane < CH && n < N_NODES) {
            int v2 = off + sincl - sv;
            p.rowp[n] = v2;
            p.deg[n]  = v2;                         // cursor
        }
    }
    conv_slice(p, 30000, 40000, gtid);
    gsync(p.bar, 4);

    // ---- F: CSR fill + conv slice 4 -----------------------------------------
    for (int e = gtid; e < N_EDGES; e += TOTTHR) {
        int d = p.dst[e];
        int pos = atomicAdd(&p.deg[d], 1);
        p.esrc[pos] = p.src[e];
    }
    conv_slice(p, 40000, N_NODES, gtid);
    gsync(p.bar, 5);

    // ---- G: mean aggregation (wave per node) --------------------------------
    for (int n = gwid; n < N_NODES; n += NWAVE) {
        int s0 = __builtin_amdgcn_readfirstlane(p.rowp[n]);
        int s1 = __builtin_amdgcn_readfirstlane(p.rowp[n + 1]);
        float ax = 0.f, ay = 0.f;
        int e = s0;
        for (; e + 8 <= s1; e += 8) {
            int i0 = p.esrc[e],     i1 = p.esrc[e + 1], i2 = p.esrc[e + 2], i3 = p.esrc[e + 3];
            int i4 = p.esrc[e + 4], i5 = p.esrc[e + 5], i6 = p.esrc[e + 6], i7 = p.esrc[e + 7];
            unsigned u0 = ((const unsigned*)(p.xa + (size_t)i0 * LDA))[lane];
            unsigned u1 = ((const unsigned*)(p.xa + (size_t)i1 * LDA))[lane];
            unsigned u2 = ((const unsigned*)(p.xa + (size_t)i2 * LDA))[lane];
            unsigned u3 = ((const unsigned*)(p.xa + (size_t)i3 * LDA))[lane];
            unsigned u4 = ((const unsigned*)(p.xa + (size_t)i4 * LDA))[lane];
            unsigned u5 = ((const unsigned*)(p.xa + (size_t)i5 * LDA))[lane];
            unsigned u6 = ((const unsigned*)(p.xa + (size_t)i6 * LDA))[lane];
            unsigned u7 = ((const unsigned*)(p.xa + (size_t)i7 * LDA))[lane];
            ax += ((blo(u0) + blo(u1)) + (blo(u2) + blo(u3)))
                + ((blo(u4) + blo(u5)) + (blo(u6) + blo(u7)));
            ay += ((bhi(u0) + bhi(u1)) + (bhi(u2) + bhi(u3)))
                + ((bhi(u4) + bhi(u5)) + (bhi(u6) + bhi(u7)));
        }
        for (; e < s1; ++e) {
            unsigned u = ((const unsigned*)(p.xa + (size_t)p.esrc[e] * LDA))[lane];
            ax += blo(u); ay += bhi(u);
        }
        float dnm = (float)max(s1 - s0, 1);
        bf16x2 o;
        o[0] = (bf16)(ax / dnm);
        o[1] = (bf16)(ay / dnm);
        *(bf16x2*)(p.xa + (size_t)n * LDA + 128 + 2 * lane) = o;
    }
    gsync(p.bar, 6);

    // ---- H: GEMM layer 1 (xa -> x2, relu+bias) ------------------------------
    gemm_phase(p.xa, p.wt1, p.b1, p.x2, true, As, Bs, bid, tid);
    gsync(p.bar, 7);

    // ---- I: GEMM layer 2 (x2 -> P, P overlays xa) ---------------------------
    gemm_phase(p.x2, p.wt2, nullptr, p.xa, false, As, Bs, bid, tid);
    gsync(p.bar, 8);

    // ---- J: layer-2 aggregate + epilogue + partial pool ---------------------
    {
        const bf16* P = p.xa;
        float2 bfv = *(const float2*)(p.b2 + 2 * lane);
        float csx = 0.f, csy = 0.f;
        for (int n = gwid; n < N_NODES; n += NWAVE) {
            int s0 = __builtin_amdgcn_readfirstlane(p.rowp[n]);
            int s1 = __builtin_amdgcn_readfirstlane(p.rowp[n + 1]);
            float ax = 0.f, ay = 0.f;
            int e = s0;
            for (; e + 8 <= s1; e += 8) {
                int i0 = p.esrc[e],     i1 = p.esrc[e + 1], i2 = p.esrc[e + 2], i3 = p.esrc[e + 3];
                int i4 = p.esrc[e + 4], i5 = p.esrc[e + 5], i6 = p.esrc[e + 6], i7 = p.esrc[e + 7];
                unsigned u0 = ((const unsigned*)(P + (size_t)i0 * LDA + H2))[lane];
                unsigned u1 = ((const unsigned*)(P + (size_t)i1 * LDA + H2))[lane];
                unsigned u2 = ((const unsigned*)(P + (size_t)i2 * LDA + H2))[lane];
                unsigned u3 = ((const unsigned*)(P + (size_t)i3 * LDA + H2))[lane];
                unsigned u4 = ((const unsigned*)(P + (size_t)i4 * LDA + H2))[lane];
                unsigned u5 = ((const unsigned*)(P + (size_t)i5 * LDA + H2))[lane];
                unsigned u6 = ((const unsigned*)(P + (size_t)i6 * LDA + H2))[lane];
                unsigned u7 = ((const unsigned*)(P + (size_t)i7 * LDA + H2))[lane];
                ax += ((blo(u0) + blo(u1)) + (blo(u2) + blo(u3)))
                    + ((blo(u4) + blo(u5)) + (blo(u6) + blo(u7)));
                ay += ((bhi(u0) + bhi(u1)) + (bhi(u2) + bhi(u3)))
                    + ((bhi(u4) + bhi(u5)) + (bhi(u6) + bhi(u7)));
            }
            for (; e < s1; ++e) {
                unsigned u = ((const unsigned*)(P + (size_t)p.esrc[e] * LDA + H2))[lane];
                ax += blo(u); ay += bhi(u);
            }
            float dnm = (float)max(s1 - s0, 1);
            unsigned us = ((const unsigned*)(P + (size_t)n * LDA))[lane];
            float yx = blo(us) + ax / dnm + bfv.x;
            float yy = bhi(us) + ay / dnm + bfv.y;
            csx += fmaxf(yx, 0.f);
            csy += fmaxf(yy, 0.f);
        }
        *(float2*)(p.part + (size_t)gwid * 128 + 2 * lane) = make_float2(csx, csy);
    }
    gsync(p.bar, 9);

    // ---- K: reduce partials -> hg[128] (128 blocks, one feature each) -------
    if (bid < 128) {
        int f = bid;
        float s = 0.f;
        for (int i = tid; i < NROWS; i += 256) s += p.part[(size_t)i * 128 + f];
        #pragma unroll
        for (int off = 32; off >= 1; off >>= 1) s += __shfl_down(s, off);
        if (lane == 0) rls[wv] = s;
        __syncthreads();
        if (tid == 0) p.hg[f] = (rls[0] + rls[1]) + (rls[2] + rls[3]);
    }
    gsync(p.bar, 10);

    // ---- L: mean + MLP head (block 0) ---------------------------------------
    if (bid == 0) {
        int t = tid;
        if (t < 128) h0[t] = p.hg[t] * (1.0f / N_NODES);
        __syncthreads();
        if (t < 64) {
            float s = p.f1b[t];
            for (int k = 0; k < 128; ++k) s += h0[k] * p.f1w[k * 64 + t];
            y1[t] = fmaxf(s, 0.f);
        }
        __syncthreads();
        if (t < 32) {
            float s = p.f2b[t];
            for (int k = 0; k < 64; ++k) s += y1[k] * p.f2w[k * 32 + t];
            y2[t] = fmaxf(s, 0.f);
        }
        __syncthreads();
        if (t == 0) {
            float s = p.f3b[0];
            for (int k = 0; k < 32; ++k) s += y2[k] * p.f3w[k];
            p.out[0] = s;
        }
    }
}

extern "C" void kernel_launch(void* const* d_in, const int* in_sizes, int n_in,
                              void* d_out, int out_size, void* d_ws, size_t ws_size,
                              hipStream_t stream) {
    (void)in_sizes; (void)n_in; (void)out_size; (void)ws_size;
    char* ws = (char*)d_ws;
    Par p;
    p.h   = (const float*)d_in[0];
    p.src = (const int*)d_in[1];
    p.dst = (const int*)d_in[2];
    p.cw  = (const float*)d_in[3];
    p.cb  = (const float*)d_in[4];
    p.ws1 = (const float*)d_in[5];
    p.wn1 = (const float*)d_in[6];
    p.b1  = (const float*)d_in[7];
    p.ws2 = (const float*)d_in[8];
    p.wn2 = (const float*)d_in[9];
    p.b2  = (const float*)d_in[10];
    p.f1w = (const float*)d_in[11];
    p.f1b = (const float*)d_in[12];
    p.f2w = (const float*)d_in[13];
    p.f2b = (const float*)d_in[14];
    p.f3w = (const float*)d_in[15];
    p.f3b = (const float*)d_in[16];
    p.out = (float*)d_out;

    // workspace layout (bytes, 256-aligned); P overlays xa (xa dead after gemm1)
    p.xa   = (bf16*) (ws + 0);           // 50048*256*2 = 25,624,576
    p.x2   = (bf16*) (ws + 25624576);    // 25,624,576
    p.wt1  = (bf16*) (ws + 51249152);    // 131,072
    p.wt2  = (bf16*) (ws + 51380224);    // 131,072
    p.deg  = (int*)  (ws + 51511296);    // 200,192 (also cursor)
    p.rowp = (int*)  (ws + 51711488);    // 200,448
    p.esrc = (int*)  (ws + 51911936);    // 3,200,000
    p.part = (float*)(ws + 55111936);    // 4096*128*4 = 2,097,152
    p.hg   = (float*)(ws + 57209088);    // 512
    p.bsum = (int*)  (ws + 57209600);    // 4,096
    p.bar  = (int*)  (ws + 57213696);    // 1,536  (total ~57.2 MB)

    hipMemsetAsync(p.bar, 0, 1536, stream);       // barrier counters
    mega<<<NBLK, NTHR, 0, stream>>>(p);
}

// Round 3
// 538.002 us; speedup vs baseline: 6.2029x; 6.2029x over previous
//
#include <hip/hip_runtime.h>

#define N_NODES 50000
#define N_EDGES 800000
#define IN_DIM  1024
#define COUT    127
#define H1      256
#define H2      128
#define LDA     256          // row stride (elements) of xa / x2 / P
#define MBLK    391          // ceil(50000/128)
#define EPB     2048         // agg_epi blocks (4 waves each -> 8192 partial rows)
#define NROWS   8192         // partial rows
#define LDSS    72           // LDS row stride (elems) for MFMA tiles: 144 B -> 2-way only
#define EBLK    782          // edge blocks at 1024 thr (782*1024 >= 800000)
#define CVB     256          // conv blocks fused beside CSR phases

typedef __bf16 bf16;
typedef __attribute__((ext_vector_type(8))) __bf16 bf16x8;
typedef __attribute__((ext_vector_type(2))) __bf16 bf16x2;
typedef __attribute__((ext_vector_type(4))) float floatx4;

__device__ __forceinline__ float blo(unsigned int u) { return __uint_as_float(u << 16); }
__device__ __forceinline__ float bhi(unsigned int u) { return __uint_as_float(u & 0xffff0000u); }

// ---- conv1d range: h[N,1024] -> xa[:, 0:128] bf16 (col 127 = 0) ------------
// 1024-thr blocks: 8 nodes per block-iteration. cb in [0,ncb).
__device__ __forceinline__ void conv_range(const float* __restrict__ h,
                                           const float* __restrict__ w, float bb,
                                           bf16* __restrict__ xa,
                                           int lo, int hi, int cb, int ncb) {
    int t   = threadIdx.x & 127;                   // 0..127
    int sub = threadIdx.x >> 7;                    // 0..7
    float wv[10];
    #pragma unroll
    for (int j = 0; j < 10; ++j) wv[j] = w[j];
    for (int n = lo + cb * 8 + sub; n < hi; n += ncb * 8) {
        const float* hr = h + (size_t)n * IN_DIM;
        float r = 0.f;
        if (t < COUT) {
            const float* q = hr + t * 8;           // 32B aligned
            float4 a = *(const float4*)q;
            float4 c = *(const float4*)(q + 4);
            float2 d = *(const float2*)(q + 8);
            float s = bb;
            s += a.x * wv[0] + a.y * wv[1] + a.z * wv[2] + a.w * wv[3];
            s += c.x * wv[4] + c.y * wv[5] + c.z * wv[6] + c.w * wv[7];
            s += d.x * wv[8] + d.y * wv[9];
            r = fmaxf(s, 0.f);
        }
        xa[(size_t)n * LDA + t] = (bf16)r;
    }
}

// ---- merged: WT1 / WT2 transposed-pad weights + zero deg -------------------
__global__ void padw_kernel(const float* __restrict__ ws1, const float* __restrict__ wn1,
                            const float* __restrict__ ws2, const float* __restrict__ wn2,
                            bf16* __restrict__ wt1, bf16* __restrict__ wt2,
                            int* __restrict__ deg) {
    int i = blockIdx.x * blockDim.x + threadIdx.x; // 0 .. 131071
    int j = i & 65535;
    int n = j >> 8, k = j & 255;
    if (i < 65536) {
        float v = 0.f;
        if (k < COUT)                        v = ws1[k * H1 + n];
        else if (k >= 128 && k < 128 + COUT) v = wn1[(k - 128) * H1 + n];
        wt1[j] = (bf16)v;
    } else {
        float v = (n < H2) ? ws2[k * H2 + n] : wn2[k * H2 + (n - H2)];
        wt2[j] = (bf16)v;
    }
    if (i < 50048) deg[i] = 0;
}

// ---- deg atomics (blocks 0..781) + conv nodes [0,25000) (blocks 782..1037) -
__global__ __launch_bounds__(1024) void deg_conv_kernel(
        const int* __restrict__ dst, int* __restrict__ deg,
        const float* __restrict__ h, const float* __restrict__ cw,
        const float* __restrict__ cb, bf16* __restrict__ xa) {
    int bid = blockIdx.x;
    if (bid < EBLK) {
        int e = bid * 1024 + threadIdx.x;
        if (e < N_EDGES) atomicAdd(&deg[dst[e]], 1);
    } else {
        conv_range(h, cw, cb[0], xa, 0, 25000, bid - EBLK, CVB);
    }
}

// ---- scan (block 0, 8 elems/thread, 7 serial chunks) -----------------------
__device__ void scan_block(const int* __restrict__ deg, int* __restrict__ rowptr,
                           int* __restrict__ cursor) {
    __shared__ int wsum[16];
    __shared__ int carry_s;
    int tid = threadIdx.x;
    int lane = tid & 63, wid = tid >> 6;
    if (tid == 0) carry_s = 0;
    __syncthreads();
    for (int base = 0; base < N_NODES; base += 8192) {
        int i0 = base + tid * 8;
        int v[8];
        if (i0 + 8 <= N_NODES) {
            int4 a = *(const int4*)&deg[i0];
            int4 c = *(const int4*)&deg[i0 + 4];
            v[0] = a.x; v[1] = a.y; v[2] = a.z; v[3] = a.w;
            v[4] = c.x; v[5] = c.y; v[6] = c.z; v[7] = c.w;
        } else {
            #pragma unroll
            for (int j = 0; j < 8; ++j) v[j] = (i0 + j < N_NODES) ? deg[i0 + j] : 0;
        }
        int p[8]; int run = 0;
        #pragma unroll
        for (int j = 0; j < 8; ++j) { run += v[j]; p[j] = run; }
        int s = run;
        #pragma unroll
        for (int off = 1; off < 64; off <<= 1) {
            int t = __shfl_up(s, off);
            if (lane >= off) s += t;
        }
        if (lane == 63) wsum[wid] = s;
        __syncthreads();
        if (tid < 16) {
            int ws = wsum[tid];
            #pragma unroll
            for (int off = 1; off < 16; off <<= 1) {
                int t = __shfl_up(ws, off);
                if (tid >= off) ws += t;
            }
            wsum[tid] = ws;
        }
        __syncthreads();
        int wpre  = (wid == 0) ? 0 : wsum[wid - 1];
        int excl0 = carry_s + wpre + (s - run);
        int o[8];
        #pragma unroll
        for (int j = 0; j < 8; ++j) o[j] = excl0 + p[j] - v[j];
        if (i0 + 8 <= N_NODES) {
            *(int4*)&rowptr[i0]     = make_int4(o[0], o[1], o[2], o[3]);
            *(int4*)&rowptr[i0 + 4] = make_int4(o[4], o[5], o[6], o[7]);
            *(int4*)&cursor[i0]     = make_int4(o[0], o[1], o[2], o[3]);
            *(int4*)&cursor[i0 + 4] = make_int4(o[4], o[5], o[6], o[7]);
        } else {
            for (int j = 0; j < 8; ++j)
                if (i0 + j < N_NODES) { rowptr[i0 + j] = o[j]; cursor[i0 + j] = o[j]; }
        }
        int tot = wsum[15];
        __syncthreads();
        if (tid == 0) carry_s += tot;
        __syncthreads();
    }
    if (tid == 0) rowptr[N_NODES] = carry_s;
}

// ---- scan (block 0) + conv nodes [25000,50000) (blocks 1..256) -------------
__global__ __launch_bounds__(1024) void scan_conv_kernel(
        const int* __restrict__ deg, int* __restrict__ rowptr, int* __restrict__ cursor,
        const float* __restrict__ h, const float* __restrict__ cw,
        const float* __restrict__ cb, bf16* __restrict__ xa) {
    if (blockIdx.x == 0) {
        scan_block(deg, rowptr, cursor);
    } else {
        conv_range(h, cw, cb[0], xa, 25000, N_NODES, blockIdx.x - 1, CVB);
    }
}

__global__ __launch_bounds__(1024) void fill_kernel(
        const int* __restrict__ src, const int* __restrict__ dst,
        int* __restrict__ cursor, int* __restrict__ esrc) {
    int e = blockIdx.x * 1024 + threadIdx.x;
    if (e < N_EDGES) {
        int d = dst[e];
        int pos = atomicAdd(&cursor[d], 1);
        esrc[pos] = src[e];
    }
}

// ---- mean aggregation: xa[:, 128:256] = mean of in-neighbor xa[:, 0:128] ---
// wave-per-node: 64 lanes x u32 (bf16x2) = one 256B row per load instruction.
__global__ __launch_bounds__(256) void agg_kernel(bf16* __restrict__ xa,
                                                  const int* __restrict__ rowptr,
                                                  const int* __restrict__ esrc) {
    int lane = threadIdx.x & 63;
    int w    = threadIdx.x >> 6;
    int n    = blockIdx.x * 4 + w;                 // grid = 12500 -> exact
    int s0 = __builtin_amdgcn_readfirstlane(rowptr[n]);
    int s1 = __builtin_amdgcn_readfirstlane(rowptr[n + 1]);
    float ax = 0.f, ay = 0.f;
    int e = s0;
    for (; e + 8 <= s1; e += 8) {
        int i0 = esrc[e],     i1 = esrc[e + 1], i2 = esrc[e + 2], i3 = esrc[e + 3];
        int i4 = esrc[e + 4], i5 = esrc[e + 5], i6 = esrc[e + 6], i7 = esrc[e + 7];
        unsigned u0 = ((const unsigned*)(xa + (size_t)i0 * LDA))[lane];
        unsigned u1 = ((const unsigned*)(xa + (size_t)i1 * LDA))[lane];
        unsigned u2 = ((const unsigned*)(xa + (size_t)i2 * LDA))[lane];
        unsigned u3 = ((const unsigned*)(xa + (size_t)i3 * LDA))[lane];
        unsigned u4 = ((const unsigned*)(xa + (size_t)i4 * LDA))[lane];
        unsigned u5 = ((const unsigned*)(xa + (size_t)i5 * LDA))[lane];
        unsigned u6 = ((const unsigned*)(xa + (size_t)i6 * LDA))[lane];
        unsigned u7 = ((const unsigned*)(xa + (size_t)i7 * LDA))[lane];
        ax += ((blo(u0) + blo(u1)) + (blo(u2) + blo(u3)))
            + ((blo(u4) + blo(u5)) + (blo(u6) + blo(u7)));
        ay += ((bhi(u0) + bhi(u1)) + (bhi(u2) + bhi(u3)))
            + ((bhi(u4) + bhi(u5)) + (bhi(u6) + bhi(u7)));
    }
    for (; e < s1; ++e) {
        unsigned u = ((const unsigned*)(xa + (size_t)esrc[e] * LDA))[lane];
        ax += blo(u); ay += bhi(u);
    }
    float dnm = (float)max(s1 - s0, 1);
    bf16x2 o;
    o[0] = (bf16)(ax / dnm);
    o[1] = (bf16)(ay / dnm);
    *(bf16x2*)(xa + (size_t)n * LDA + 128 + 2 * lane) = o;
}

// ---- MFMA GEMM: out[N,256] = (relu?)(X[N,256] @ W[256,256] (+bias)), bf16 --
template <bool RELU>
__global__ __launch_bounds__(256) void gemm_mfma(
        const bf16* __restrict__ X, const bf16* __restrict__ WT,
        const float* __restrict__ bias, bf16* __restrict__ out) {
    __shared__ bf16 As[128 * LDSS];                // 18432 B
    __shared__ bf16 Bs[64 * LDSS];                 //  9216 B
    int tid  = threadIdx.x;
    int lane = tid & 63, w = tid >> 6;
    int quad = lane >> 4, l16 = lane & 15;
    int m0 = blockIdx.x * 128;
    int n0 = blockIdx.y * 64;
    floatx4 acc[2][4] = {};

    for (int k0 = 0; k0 < 256; k0 += 64) {
        uint4 av[4], bv[2];
        #pragma unroll
        for (int i = 0; i < 4; ++i) {
            int c = tid + 256 * i;
            int row = c >> 3, col = (c & 7) * 8;
            int gr = m0 + row;
            av[i] = (gr < N_NODES) ? *(const uint4*)(X + (size_t)gr * LDA + k0 + col)
                                   : make_uint4(0u, 0u, 0u, 0u);
        }
        #pragma unroll
        for (int i = 0; i < 2; ++i) {
            int c = tid + 256 * i;
            int row = c >> 3, col = (c & 7) * 8;
            bv[i] = *(const uint4*)(WT + (size_t)(n0 + row) * 256 + k0 + col);
        }
        __syncthreads();
        #pragma unroll
        for (int i = 0; i < 4; ++i) {
            int c = tid + 256 * i;
            int row = c >> 3, col = (c & 7) * 8;
            *(uint4*)&As[row * LDSS + col] = av[i];
        }
        #pragma unroll
        for (int i = 0; i < 2; ++i) {
            int c = tid + 256 * i;
            int row = c >> 3, col = (c & 7) * 8;
            *(uint4*)&Bs[row * LDSS + col] = bv[i];
        }
        __syncthreads();

        #pragma unroll
        for (int ks = 0; ks < 2; ++ks) {
            int kin = ks * 32 + quad * 8;
            bf16x8 a0 = *(const bf16x8*)&As[(w * 32 + l16) * LDSS + kin];
            bf16x8 a1 = *(const bf16x8*)&As[(w * 32 + 16 + l16) * LDSS + kin];
            bf16x8 b0 = *(const bf16x8*)&Bs[(l16) * LDSS + kin];
            bf16x8 b1 = *(const bf16x8*)&Bs[(16 + l16) * LDSS + kin];
            bf16x8 b2 = *(const bf16x8*)&Bs[(32 + l16) * LDSS + kin];
            bf16x8 b3 = *(const bf16x8*)&Bs[(48 + l16) * LDSS + kin];
            acc[0][0] = __builtin_amdgcn_mfma_f32_16x16x32_bf16(a0, b0, acc[0][0], 0, 0, 0);
            acc[0][1] = __builtin_amdgcn_mfma_f32_16x16x32_bf16(a0, b1, acc[0][1], 0, 0, 0);
            acc[0][2] = __builtin_amdgcn_mfma_f32_16x16x32_bf16(a0, b2, acc[0][2], 0, 0, 0);
            acc[0][3] = __builtin_amdgcn_mfma_f32_16x16x32_bf16(a0, b3, acc[0][3], 0, 0, 0);
            acc[1][0] = __builtin_amdgcn_mfma_f32_16x16x32_bf16(a1, b0, acc[1][0], 0, 0, 0);
            acc[1][1] = __builtin_amdgcn_mfma_f32_16x16x32_bf16(a1, b1, acc[1][1], 0, 0, 0);
            acc[1][2] = __builtin_amdgcn_mfma_f32_16x16x32_bf16(a1, b2, acc[1][2], 0, 0, 0);
            acc[1][3] = __builtin_amdgcn_mfma_f32_16x16x32_bf16(a1, b3, acc[1][3], 0, 0, 0);
        }
    }

    float bvv[4] = {};
    if constexpr (RELU) {
        #pragma unroll
        for (int nt = 0; nt < 4; ++nt) bvv[nt] = bias[n0 + nt * 16 + l16];
    }
    #pragma unroll
    for (int mt = 0; mt < 2; ++mt) {
        #pragma unroll
        for (int r = 0; r < 4; ++r) {
            int m = m0 + w * 32 + mt * 16 + quad * 4 + r;
            if (m < N_NODES) {
                #pragma unroll
                for (int nt = 0; nt < 4; ++nt) {
                    float v = acc[mt][nt][r];
                    if constexpr (RELU) v = fmaxf(v + bvv[nt], 0.f);
                    out[(size_t)m * LDA + n0 + nt * 16 + l16] = (bf16)v;
                }
            }
        }
    }
}

// ---- layer-2 aggregate + epilogue + partial pool ---------------------------
__global__ __launch_bounds__(256) void agg_epi_kernel(
        const bf16* __restrict__ P, const int* __restrict__ rowptr,
        const int* __restrict__ esrc, const float* __restrict__ b2,
        float* __restrict__ partial) {
    int lane = threadIdx.x & 63;
    int w    = threadIdx.x >> 6;
    int wid  = blockIdx.x * 4 + w;                 // 0..NROWS-1
    float2 bfv = *(const float2*)(b2 + 2 * lane);
    float csx = 0.f, csy = 0.f;
    for (int n = wid; n < N_NODES; n += 4 * gridDim.x) {
        int s0 = __builtin_amdgcn_readfirstlane(rowptr[n]);
        int s1 = __builtin_amdgcn_readfirstlane(rowptr[n + 1]);
        float ax = 0.f, ay = 0.f;
        int e = s0;
        for (; e + 8 <= s1; e += 8) {
            int i0 = esrc[e],     i1 = esrc[e + 1], i2 = esrc[e + 2], i3 = esrc[e + 3];
            int i4 = esrc[e + 4], i5 = esrc[e + 5], i6 = esrc[e + 6], i7 = esrc[e + 7];
            unsigned u0 = ((const unsigned*)(P + (size_t)i0 * LDA + H2))[lane];
            unsigned u1 = ((const unsigned*)(P + (size_t)i1 * LDA + H2))[lane];
            unsigned u2 = ((const unsigned*)(P + (size_t)i2 * LDA + H2))[lane];
            unsigned u3 = ((const unsigned*)(P + (size_t)i3 * LDA + H2))[lane];
            unsigned u4 = ((const unsigned*)(P + (size_t)i4 * LDA + H2))[lane];
            unsigned u5 = ((const unsigned*)(P + (size_t)i5 * LDA + H2))[lane];
            unsigned u6 = ((const unsigned*)(P + (size_t)i6 * LDA + H2))[lane];
            unsigned u7 = ((const unsigned*)(P + (size_t)i7 * LDA + H2))[lane];
            ax += ((blo(u0) + blo(u1)) + (blo(u2) + blo(u3)))
                + ((blo(u4) + blo(u5)) + (blo(u6) + blo(u7)));
            ay += ((bhi(u0) + bhi(u1)) + (bhi(u2) + bhi(u3)))
                + ((bhi(u4) + bhi(u5)) + (bhi(u6) + bhi(u7)));
        }
        for (; e < s1; ++e) {
            unsigned u = ((const unsigned*)(P + (size_t)esrc[e] * LDA + H2))[lane];
            ax += blo(u); ay += bhi(u);
        }
        float dnm = (float)max(s1 - s0, 1);
        unsigned us = ((const unsigned*)(P + (size_t)n * LDA))[lane];
        float yx = blo(us) + ax / dnm + bfv.x;
        float yy = bhi(us) + ay / dnm + bfv.y;
        csx += fmaxf(yx, 0.f);
        csy += fmaxf(yy, 0.f);
    }
    *(float2*)(partial + (size_t)wid * 128 + 2 * lane) = make_float2(csx, csy);
}

// ---- reduce partials: hg[f] = sum_b partial[b][f] --------------------------
__global__ __launch_bounds__(256) void reduce_kernel(const float* __restrict__ partial,
                                                     float* __restrict__ hg) {
    int f = blockIdx.x, t = threadIdx.x;
    float s = 0.f;
    for (int i = t; i < NROWS; i += 256) s += partial[(size_t)i * 128 + f];
    __shared__ float ls[4];
    #pragma unroll
    for (int off = 32; off >= 1; off >>= 1) s += __shfl_down(s, off);
    if ((t & 63) == 0) ls[t >> 6] = s;
    __syncthreads();
    if (t == 0) hg[f] = (ls[0] + ls[1]) + (ls[2] + ls[3]);
}

// ---------------- mean + MLP head (single block, fp32) ----------------------
__global__ void mlp_kernel(const float* __restrict__ hg,
                           const float* __restrict__ f1w, const float* __restrict__ f1b,
                           const float* __restrict__ f2w, const float* __restrict__ f2b,
                           const float* __restrict__ f3w, const float* __restrict__ f3b,
                           float* __restrict__ out) {
    __shared__ float h0[128], y1[64], y2[32];
    int t = threadIdx.x;
    if (t < 128) h0[t] = hg[t] * (1.0f / N_NODES);
    __syncthreads();
    if (t < 64) {
        float s = f1b[t];
        for (int k = 0; k < 128; ++k) s += h0[k] * f1w[k * 64 + t];
        y1[t] = fmaxf(s, 0.f);
    }
    __syncthreads();
    if (t < 32) {
        float s = f2b[t];
        for (int k = 0; k < 64; ++k) s += y1[k] * f2w[k * 32 + t];
        y2[t] = fmaxf(s, 0.f);
    }
    __syncthreads();
    if (t == 0) {
        float s = f3b[0];
        for (int k = 0; k < 32; ++k) s += y2[k] * f3w[k];
        out[0] = s;
    }
}

extern "C" void kernel_launch(void* const* d_in, const int* in_sizes, int n_in,
                              void* d_out, int out_size, void* d_ws, size_t ws_size,
                              hipStream_t stream) {
    (void)in_sizes; (void)n_in; (void)out_size; (void)ws_size;
    const float* h        = (const float*)d_in[0];
    const int*   src      = (const int*)d_in[1];
    const int*   dst      = (const int*)d_in[2];
    const float* cw       = (const float*)d_in[3];
    const float* cb       = (const float*)d_in[4];
    const float* w_self1  = (const float*)d_in[5];
    const float* w_neigh1 = (const float*)d_in[6];
    const float* b1       = (const float*)d_in[7];
    const float* w_self2  = (const float*)d_in[8];
    const float* w_neigh2 = (const float*)d_in[9];
    const float* b2       = (const float*)d_in[10];
    const float* f1w      = (const float*)d_in[11];
    const float* f1b      = (const float*)d_in[12];
    const float* f2w      = (const float*)d_in[13];
    const float* f2b      = (const float*)d_in[14];
    const float* f3w      = (const float*)d_in[15];
    const float* f3b      = (const float*)d_in[16];
    float* out = (float*)d_out;

    // workspace (bytes, 256-aligned); P overlays xa (xa dead after gemm1)
    char* ws = (char*)d_ws;
    bf16*  xa    = (bf16*) (ws + 0);           // 50048*256*2 = 25,624,576
    bf16*  P     = (bf16*) (ws + 0);           // overlay
    bf16*  x2    = (bf16*) (ws + 25624576);    // 25,624,576
    bf16*  wt1   = (bf16*) (ws + 51249152);    // 131,072
    bf16*  wt2   = (bf16*) (ws + 51380224);    // 131,072
    int*   deg   = (int*)  (ws + 51511296);    // 200,192 (also cursor)
    int*   rowp  = (int*)  (ws + 51711488);    // 200,448
    int*   esrc  = (int*)  (ws + 51911936);    // 3,200,000
    float* part  = (float*)(ws + 55111936);    // 8192*128*4 = 4,194,304
    float* hg    = (float*)(ws + 59306240);    // 512     (total ~59.3 MB)
    int*   cur   = deg;                        // alias: deg dead after scan

    padw_kernel<<<512, 256, 0, stream>>>(w_self1, w_neigh1, w_self2, w_neigh2, wt1, wt2, deg);
    deg_conv_kernel<<<EBLK + CVB, 1024, 0, stream>>>(dst, deg, h, cw, cb, xa);
    scan_conv_kernel<<<1 + CVB, 1024, 0, stream>>>(deg, rowp, cur, h, cw, cb, xa);
    fill_kernel<<<EBLK, 1024, 0, stream>>>(src, dst, cur, esrc);
    agg_kernel<<<12500, 256, 0, stream>>>(xa, rowp, esrc);
    dim3 g(MBLK, 4);
    gemm_mfma<true><<<g, 256, 0, stream>>>(xa, wt1, b1, x2);
    gemm_mfma<false><<<g, 256, 0, stream>>>(x2, wt2, nullptr, P);
    agg_epi_kernel<<<EPB, 256, 0, stream>>>(P, rowp, esrc, b2, part);
    reduce_kernel<<<128, 256, 0, stream>>>(part, hg);
    mlp_kernel<<<1, 128, 0, stream>>>(hg, f1w, f1b, f2w, f2b, f3w, f3b, out);
}